// Round 4
// baseline (272.411 us; speedup 1.0000x reference)
//
#include <hip/hip_runtime.h>
#include <hip/hip_bf16.h>

#define NS 256    // n_state
#define MO 128    // n_obs
#define BB 64     // batch
#define TT 1024   // time steps
#define CCH 64    // chunks per batch
#define SS 16     // steps per chunk

typedef short s16x8 __attribute__((ext_vector_type(8)));
typedef float f32x4 __attribute__((ext_vector_type(4)));
typedef unsigned int uint;
typedef unsigned short ushort;

__device__ __forceinline__ ushort f2bf(float x) {
    uint u = __float_as_uint(x);
    uint r = (u + 0x7fffu + ((u >> 16) & 1u)) >> 16;
    return (ushort)r;
}
__device__ __forceinline__ float bf2f(ushort h) { return __uint_as_float(((uint)h) << 16); }

__device__ __forceinline__ uint pkbf2(float a, float b) {
    __hip_bfloat162 h = __float22bfloat162_rn(make_float2(a, b));
    union { __hip_bfloat162 b2; uint u; } cv;
    cv.b2 = h;
    return cv.u;
}

// split 8 fp32 into bf16 hi + lo fragments (element order = k ascending)
__device__ __forceinline__ void conv8(float4 f0, float4 f1, s16x8& vh, s16x8& vl) {
    uint h0 = pkbf2(f0.x, f0.y), h1 = pkbf2(f0.z, f0.w);
    uint h2 = pkbf2(f1.x, f1.y), h3 = pkbf2(f1.z, f1.w);
    float r0 = f0.x - __uint_as_float(h0 << 16);
    float r1 = f0.y - __uint_as_float(h0 & 0xffff0000u);
    float r2 = f0.z - __uint_as_float(h1 << 16);
    float r3 = f0.w - __uint_as_float(h1 & 0xffff0000u);
    float r4 = f1.x - __uint_as_float(h2 << 16);
    float r5 = f1.y - __uint_as_float(h2 & 0xffff0000u);
    float r6 = f1.z - __uint_as_float(h3 << 16);
    float r7 = f1.w - __uint_as_float(h3 & 0xffff0000u);
    uint l0 = pkbf2(r0, r1), l1 = pkbf2(r2, r3);
    uint l2 = pkbf2(r4, r5), l3 = pkbf2(r6, r7);
    union { uint u[4]; s16x8 v; } ch, cl;
    ch.u[0] = h0; ch.u[1] = h1; ch.u[2] = h2; ch.u[3] = h3;
    cl.u[0] = l0; cl.u[1] = l1; cl.u[2] = l2; cl.u[3] = l3;
    vh = ch.v; vl = cl.v;
}

__device__ __forceinline__ f32x4 mfma16(s16x8 a, s16x8 b, f32x4 c) {
    return __builtin_amdgcn_mfma_f32_16x16x32_bf16(a, b, c, 0, 0, 0);
}

// ---------------- small setup kernels (fp32, proven) ----------------

__global__ void kh_kernel(const float* __restrict__ K, const float* __restrict__ H,
                          float* __restrict__ KH) {
    int i = blockIdx.x, j = threadIdx.x;
    __shared__ float kl[MO];
    if (j < MO) kl[j] = K[i * MO + j];
    __syncthreads();
    float acc = 0.f;
#pragma unroll 8
    for (int k = 0; k < MO; ++k) acc += kl[k] * H[k * NS + j];
    KH[i * NS + j] = acc;
}

__global__ void aeff_kernel(const float* __restrict__ A, const float* __restrict__ KH,
                            float* __restrict__ AE) {
    int i = blockIdx.x, j = threadIdx.x;
    __shared__ float khr[NS];
    khr[j] = KH[i * NS + j];
    __syncthreads();
    float acc = A[i * NS + j];
#pragma unroll 8
    for (int k = 0; k < NS; ++k) acc -= khr[k] * A[k * NS + j];
    AE[i * NS + j] = acc;
}

__global__ void matsq_kernel(const float* __restrict__ src, float* __restrict__ dst) {
    int i = blockIdx.x, j = threadIdx.x;
    __shared__ float row[NS];
    row[j] = src[i * NS + j];
    __syncthreads();
    float acc = 0.f;
#pragma unroll 8
    for (int k = 0; k < NS; ++k) acc += row[k] * src[k * NS + j];
    dst[i * NS + j] = acc;
}

// Convert AE, M(A^16), M2(A^128), K to bf16 hi/lo pairs. grid 896.
__global__ void conv_kernel(const float* __restrict__ AE, const float* __restrict__ M,
                            const float* __restrict__ M2, const float* __restrict__ K,
                            ushort* __restrict__ aeh, ushort* __restrict__ ael,
                            ushort* __restrict__ mh, ushort* __restrict__ ml,
                            ushort* __restrict__ m2h, ushort* __restrict__ m2l,
                            ushort* __restrict__ kbh, ushort* __restrict__ kbl) {
    int blk = blockIdx.x;
    if (blk >= 768) {
        int i = (blk - 768) * 256 + threadIdx.x;  // 0..32767
        float v = K[i];
        ushort hi = f2bf(v);
        kbh[i] = hi;
        kbl[i] = f2bf(v - bf2f(hi));
        return;
    }
    int i = (blk & 255) * 256 + threadIdx.x;
    int mat = blk >> 8;
    const float* src = (mat == 0) ? AE : ((mat == 1) ? M : M2);
    ushort* dh = (mat == 0) ? aeh : ((mat == 1) ? mh : m2h);
    ushort* dl = (mat == 0) ? ael : ((mat == 1) ? ml : m2l);
    float v = src[i];
    ushort hi = f2bf(v);
    dh[i] = hi;
    dl[i] = f2bf(v - bf2f(hi));
}

// ---------------- MFMA serial scan ----------------
// MODE 0 (A):  fused u=y@K^T, local chunk scans from 0, S=16, store e.   grid 256
// MODE 1 (Ba): u=e_buf, S=8, store e2.                                   grid 32
// MODE 2 (Bb): u=e2, S=8, write c2[b,s+1], c2[b,0]=0.                    grid 4
// MODE 3 (Bc): u=e_buf, cin=c2, S=8, write cbuf.                         grid 32
// MODE 4 (C):  fused u=y@K^T, cin=cbuf, S=16, write out each step.       grid 256

template <int MODE>
__launch_bounds__(512, 2)
__global__ void scan16_kernel(const ushort* __restrict__ mh, const ushort* __restrict__ ml,
                              const ushort* __restrict__ kbh, const ushort* __restrict__ kbl,
                              const float* __restrict__ y_g,
                              const float* u, const float* __restrict__ cin,
                              float* wout, float* __restrict__ eout) {
    constexpr bool YF = (MODE == 0 || MODE == 4);
    constexpr int S = YF ? SS : 8;
    const int tid = threadIdx.x;
    const int blk = blockIdx.x;
    const int w = tid >> 6;
    const int l = tid & 63;
    const int lr = l & 15;
    const int lg = l >> 4;

    __shared__ ushort xh_s[16 * NS];
    __shared__ ushort xl_s[16 * NS];
    __shared__ float ybuf[2][16 * MO];
    __shared__ float xe_s[16 * NS];

    const int b0 = (blk & 3) * 16;  // YF modes
    const int cc = blk >> 2;        // YF modes
    const int t0 = cc * SS;         // YF modes

    auto ubase = [&](int m) -> long {
        if constexpr (MODE == 1 || MODE == 3) {
            int rid = blk * 16 + m;
            int b = rid >> 3, g = rid & 7;
            return ((long)b * 64 + g * 8) * NS;
        } else {
            int b = blk * 16 + m;
            return (long)b * 8 * NS;
        }
    };

    // ---- matrix B-fragments (bf16 hi/lo), 128 VGPR ----
    s16x8 Bh[2][8], Bl[2][8];
#pragma unroll
    for (int t2 = 0; t2 < 2; ++t2) {
        int row = 16 * (2 * w + t2) + lr;
#pragma unroll
        for (int q = 0; q < 8; ++q) {
            int off = row * NS + 32 * q + 8 * lg;
            Bh[t2][q] = *(const s16x8*)(mh + off);
            Bl[t2][q] = *(const s16x8*)(ml + off);
        }
    }

    // ---- K B-fragments (YF only), 64 VGPR ----
    s16x8 KBh[2][4], KBl[2][4];
    if constexpr (YF) {
#pragma unroll
        for (int t2 = 0; t2 < 2; ++t2) {
            int row = 16 * (2 * w + t2) + lr;
#pragma unroll
            for (int q = 0; q < 4; ++q) {
                int off = row * MO + 32 * q + 8 * lg;
                KBh[t2][q] = *(const s16x8*)(kbh + off);
                KBl[t2][q] = *(const s16x8*)(kbl + off);
            }
        }
    }

    // ---- init x state ----
#pragma unroll
    for (int jj = 0; jj < 8; ++jj) {
        int idx = jj * 512 + tid;  // 0..4095
        int m = idx >> 8, col = idx & 255;
        float xv = 0.f;
        if constexpr (MODE == 3) {
            int rid = blk * 16 + m;
            int b = rid >> 3, g = rid & 7;
            xv = cin[(b * 8 + g) * NS + col];
            if (g == 0) wout[(long)b * 64 * NS + col] = 0.f;  // cbuf[b,0] = 0
        } else if constexpr (MODE == 4) {
            xv = cin[((long)(b0 + m) * 64 + cc) * NS + col];
        } else if constexpr (MODE == 2) {
            int b = blk * 16 + m;
            wout[(long)b * 8 * NS + col] = 0.f;  // c2[b,0] = 0
        }
        ushort hi = f2bf(xv);
        ushort lo = f2bf(xv - bf2f(hi));
        int sidx = (m * NS + col) ^ ((m & 7) << 3);
        xh_s[sidx] = hi;
        xl_s[sidx] = lo;
    }

    const int col0 = 32 * w + lr;
    const int col1 = col0 + 16;

    // ---- y staging setup (YF): reg-prefetch 1 step ahead, swizzled LDS dbuf ----
    const int yr = tid >> 5;             // batch-row 0..15
    const int yc = (tid & 31) << 2;      // obs col 0,4,..,124
    const float* ysrc = nullptr;
    int ywbyte = 0;
    float4 vnext = make_float4(0.f, 0.f, 0.f, 0.f);
    if constexpr (YF) {
        ysrc = y_g + ((size_t)(b0 + yr) * TT + t0) * MO + yc;
        ywbyte = (yr * 512 + yc * 4) ^ ((yr & 7) << 4);
        float4 v0 = *(const float4*)(ysrc);
        *(float4*)((char*)(&ybuf[0][0]) + ywbyte) = v0;
        vnext = *(const float4*)(ysrc + MO);
    }

    // ---- u prefetch (non-YF) ----
    float up0[4], up1[4];
    if constexpr (!YF) {
#pragma unroll
        for (int i = 0; i < 4; ++i) {
            int m = 4 * lg + i;
            long ub = ubase(m);
            up0[i] = u[ub + col0];
            up1[i] = u[ub + col1];
        }
    }
    __syncthreads();

    for (int s = 0; s < S; ++s) {
        f32x4 acc0, acc1;
        if constexpr (YF) {
            acc0 = f32x4{0.f, 0.f, 0.f, 0.f};
            acc1 = f32x4{0.f, 0.f, 0.f, 0.f};
            const char* yb = (const char*)(&ybuf[s & 1][0]);
#pragma unroll
            for (int q = 0; q < 4; ++q) {
                int lb = lr * 512 + q * 128 + lg * 32;
                float4 f0 = *(const float4*)(yb + (lb ^ ((lr & 7) << 4)));
                float4 f1 = *(const float4*)(yb + ((lb + 16) ^ ((lr & 7) << 4)));
                s16x8 yh, yl;
                conv8(f0, f1, yh, yl);
                acc0 = mfma16(yh, KBh[0][q], acc0);
                acc0 = mfma16(yl, KBh[0][q], acc0);
                acc0 = mfma16(yh, KBl[0][q], acc0);
                acc1 = mfma16(yh, KBh[1][q], acc1);
                acc1 = mfma16(yl, KBh[1][q], acc1);
                acc1 = mfma16(yh, KBl[1][q], acc1);
            }
        } else {
            acc0[0] = up0[0]; acc0[1] = up0[1]; acc0[2] = up0[2]; acc0[3] = up0[3];
            acc1[0] = up1[0]; acc1[1] = up1[1]; acc1[2] = up1[2]; acc1[3] = up1[3];
        }

        // x-term: x @ M^T
#pragma unroll
        for (int q = 0; q < 8; ++q) {
            int ridx = (lr * NS + 32 * q + 8 * lg) ^ ((lr & 7) << 3);
            s16x8 xh = *(const s16x8*)&xh_s[ridx];
            s16x8 xl = *(const s16x8*)&xl_s[ridx];
            acc0 = mfma16(xh, Bh[0][q], acc0);
            acc0 = mfma16(xl, Bh[0][q], acc0);
            acc0 = mfma16(xh, Bl[0][q], acc0);
            acc1 = mfma16(xh, Bh[1][q], acc1);
            acc1 = mfma16(xl, Bh[1][q], acc1);
            acc1 = mfma16(xh, Bl[1][q], acc1);
        }

        // u prefetch for next step (non-YF)
        if constexpr (!YF) {
            if (s + 1 < S) {
#pragma unroll
                for (int i = 0; i < 4; ++i) {
                    int m = 4 * lg + i;
                    long ub = ubase(m) + (long)(s + 1) * NS;
                    up0[i] = u[ub + col0];
                    up1[i] = u[ub + col1];
                }
            }
        }

        // mode-specific stores (pre-barrier)
        if constexpr (MODE == 2) {
            if (s < 7) {
#pragma unroll
                for (int i = 0; i < 4; ++i) {
                    int m = 4 * lg + i;
                    int b = blk * 16 + m;
                    long wb = ((long)b * 8 + s + 1) * NS;
                    wout[wb + col0] = acc0[i];
                    wout[wb + col1] = acc1[i];
                }
            }
        } else if constexpr (MODE == 3) {
#pragma unroll
            for (int i = 0; i < 4; ++i) {
                int m = 4 * lg + i;
                int rid = blk * 16 + m;
                int b = rid >> 3, g = rid & 7;
                int kk = 8 * g + s + 1;
                if (kk < 64) {
                    long wb = ((long)b * 64 + kk) * NS;
                    wout[wb + col0] = acc0[i];
                    wout[wb + col1] = acc1[i];
                }
            }
        }
        if constexpr (MODE == 0 || MODE == 1) {
            if (s == S - 1) {
#pragma unroll
                for (int i = 0; i < 4; ++i) {
                    int m = 4 * lg + i;
                    long eb;
                    if constexpr (MODE == 0) {
                        eb = ((long)(b0 + m) * 64 + cc) * NS;
                    } else {
                        eb = (long)(blk * 16 + m) * NS;
                    }
                    eout[eb + col0] = acc0[i];
                    eout[eb + col1] = acc1[i];
                }
            }
        }

        __syncthreads();  // barrier1: all LDS reads of this step done

        // write new x (bf16 hi/lo) (+ fp32 tile for mode 4)
#pragma unroll
        for (int i = 0; i < 4; ++i) {
            int m = 4 * lg + i;
            {
                ushort hi = f2bf(acc0[i]);
                ushort lo = f2bf(acc0[i] - bf2f(hi));
                int wi = (m * NS + col0) ^ ((m & 7) << 3);
                xh_s[wi] = hi;
                xl_s[wi] = lo;
            }
            {
                ushort hi = f2bf(acc1[i]);
                ushort lo = f2bf(acc1[i] - bf2f(hi));
                int wi = (m * NS + col1) ^ ((m & 7) << 3);
                xh_s[wi] = hi;
                xl_s[wi] = lo;
            }
            if constexpr (MODE == 4) {
                xe_s[(m * NS + col0) ^ ((m & 7) << 2)] = acc0[i];
                xe_s[(m * NS + col1) ^ ((m & 7) << 2)] = acc1[i];
            }
        }
        // y stage: publish next step's tile, issue load for s+2
        if constexpr (YF) {
            if (s + 1 < S) {
                *(float4*)((char*)(&ybuf[(s + 1) & 1][0]) + ywbyte) = vnext;
                if (s + 2 < S) vnext = *(const float4*)(ysrc + (size_t)(s + 2) * MO);
            }
        }
        __syncthreads();  // barrier2

        // mode 4: coalesced out stores (1 full row per wave-instruction)
        if constexpr (MODE == 4) {
#pragma unroll
            for (int j = 0; j < 2; ++j) {
                int idx = j * 512 + tid;  // float4 index 0..1023
                int r = idx >> 6;
                int wb = idx << 2;        // float word index
                float4 vv = *(const float4*)&xe_s[wb ^ ((r & 7) << 2)];
                long ob = ((long)(b0 + r) * TT + (t0 + s)) * NS + (wb & 255);
                *(float4*)(wout + ob) = vv;
            }
        }
    }
}

// ---------------- launcher ----------------

extern "C" void kernel_launch(void* const* d_in, const int* in_sizes, int n_in,
                              void* d_out, int out_size, void* d_ws, size_t ws_size,
                              hipStream_t stream) {
    const float* y = (const float*)d_in[0];
    const float* A = (const float*)d_in[1];
    const float* H = (const float*)d_in[2];
    const float* K = (const float*)d_in[3];
    float* out = (float*)d_out;

    float* ws = (float*)d_ws;
    const long MAT = (long)NS * NS;  // 65536 floats
    float* KH = ws + 0 * MAT;
    float* AE = ws + 1 * MAT;
    float* W0 = ws + 2 * MAT;  // A^2
    float* W1 = ws + 3 * MAT;  // A^4
    float* W2 = ws + 4 * MAT;  // A^8
    float* W3 = ws + 5 * MAT;  // A^16  (M)
    float* W4 = ws + 6 * MAT;  // A^32
    float* W5 = ws + 7 * MAT;  // A^64
    float* W6 = ws + 8 * MAT;  // A^128 (M2)
    ushort* aeh = (ushort*)(ws + 9 * MAT);
    ushort* ael = aeh + MAT;
    ushort* mh = ael + MAT;
    ushort* ml = mh + MAT;
    ushort* m2h = ml + MAT;
    ushort* m2l = m2h + MAT;               // ends at float offset 12*MAT
    ushort* kbh = (ushort*)(ws + 12 * MAT);
    ushort* kbl = kbh + (long)NS * MO;     // ends at 12.5*MAT
    float* e_buf = ws + 13 * MAT;   // [64][64][256] = 16 MAT
    float* e2 = ws + 29 * MAT;      // [64][8][256]  = 2 MAT
    float* c2 = ws + 31 * MAT;      // [64][8][256]  = 2 MAT
    float* cbuf = ws + 33 * MAT;    // [64][64][256] = 16 MAT -> ends 49 MAT (~12.9 MB)

    kh_kernel<<<NS, NS, 0, stream>>>(K, H, KH);
    aeff_kernel<<<NS, NS, 0, stream>>>(A, KH, AE);
    matsq_kernel<<<NS, NS, 0, stream>>>(AE, W0);
    matsq_kernel<<<NS, NS, 0, stream>>>(W0, W1);
    matsq_kernel<<<NS, NS, 0, stream>>>(W1, W2);
    matsq_kernel<<<NS, NS, 0, stream>>>(W2, W3);
    matsq_kernel<<<NS, NS, 0, stream>>>(W3, W4);
    matsq_kernel<<<NS, NS, 0, stream>>>(W4, W5);
    matsq_kernel<<<NS, NS, 0, stream>>>(W5, W6);
    conv_kernel<<<896, 256, 0, stream>>>(AE, W3, W6, K, aeh, ael, mh, ml, m2h, m2l, kbh, kbl);

    // Phase A: fused local chunk scans -> e
    scan16_kernel<0><<<256, 512, 0, stream>>>(aeh, ael, kbh, kbl, y, nullptr, nullptr, nullptr, e_buf);
    // Phase Ba: superchunk local scans of e -> e2
    scan16_kernel<1><<<32, 512, 0, stream>>>(mh, ml, nullptr, nullptr, nullptr, e_buf, nullptr, nullptr, e2);
    // Phase Bb: superchunk carry scan -> c2
    scan16_kernel<2><<<4, 512, 0, stream>>>(m2h, m2l, nullptr, nullptr, nullptr, e2, nullptr, c2, nullptr);
    // Phase Bc: chunk carries -> cbuf
    scan16_kernel<3><<<32, 512, 0, stream>>>(mh, ml, nullptr, nullptr, nullptr, e_buf, c2, cbuf, nullptr);
    // Phase C: fused final scans, write out
    scan16_kernel<4><<<256, 512, 0, stream>>>(aeh, ael, kbh, kbl, y, nullptr, cbuf, out, nullptr);
}